// Round 8
// baseline (840.601 us; speedup 1.0000x reference)
//
#include <hip/hip_runtime.h>

#define NN 100000
#define NE 1600000
#define DF 128
#define NC 47
#define NCP 48

constexpr int NPAD = 100352;        // = 196 * 512, padded node count
constexpr int NBKT = 196;           // radix buckets (512 nodes each)
constexpr int ABLK = 400;           // bucket count/scatter blocks
constexpr int EPB  = NE / ABLK;     // 4000 edges per block
constexpr int CLEN = NBKT * ABLK;   // 78400 per-block-per-bucket counts

// Pass 1: per-block LDS histograms of dst>>9 and src>>9 (no global atomics).
__global__ __launch_bounds__(256) void bucketcount_kernel(const int* __restrict__ src,
        const int* __restrict__ dst, int* __restrict__ cntsD, int* __restrict__ cntsS) {
    __shared__ int hD[NBKT], hS[NBKT];
    int t = threadIdx.x;
    if (t < NBKT) { hD[t] = 0; hS[t] = 0; }
    __syncthreads();
    int base = blockIdx.x * EPB;
    for (int i = t; i < EPB; i += 256) {
        atomicAdd(&hD[dst[base + i] >> 9], 1);   // LDS atomic (workgroup scope)
        atomicAdd(&hS[src[base + i] >> 9], 1);
    }
    __syncthreads();
    if (t < NBKT) {
        cntsD[t * ABLK + blockIdx.x] = hD[t];    // bucket-major for the scan
        cntsS[t * ABLK + blockIdx.x] = hS[t];
    }
}

// Pass 2: in-place exclusive scan of each counts array (block 0: D, block 1: S).
__global__ __launch_bounds__(1024) void bucketscan_kernel(int* __restrict__ cntsD,
        int* __restrict__ cntsS) {
    int* a = blockIdx.x ? cntsS : cntsD;
    __shared__ int part[1024];
    int t = threadIdx.x;
    const int CH = (CLEN + 1023) / 1024;   // 77
    int base = t * CH;
    int s = 0;
    for (int i = 0; i < CH; i++) { int idx = base + i; if (idx < CLEN) s += a[idx]; }
    part[t] = s;
    __syncthreads();
    for (int off = 1; off < 1024; off <<= 1) {
        int v = (t >= off) ? part[t - off] : 0;
        __syncthreads();
        part[t] += v;
        __syncthreads();
    }
    int run = t ? part[t - 1] : 0;
    for (int i = 0; i < CH; i++) {
        int idx = base + i;
        if (idx < CLEN) { int v = a[idx]; a[idx] = run; run += v; }
    }
}

// Pass 3: scatter edges into bucket-sorted arrays. Position = scanned block offset +
// LDS-atomic rank. pairsD packs (src<<9)|(dst&511); pairsS needs only src&511.
__global__ __launch_bounds__(256) void bucketscatter_kernel(const int* __restrict__ src,
        const int* __restrict__ dst, const int* __restrict__ cntsD,
        const int* __restrict__ cntsS, unsigned* __restrict__ pairsD,
        unsigned short* __restrict__ pairsS) {
    __shared__ int fD[NBKT], fS[NBKT];
    int t = threadIdx.x;
    if (t < NBKT) {
        fD[t] = cntsD[t * ABLK + blockIdx.x];
        fS[t] = cntsS[t * ABLK + blockIdx.x];
    }
    __syncthreads();
    int base = blockIdx.x * EPB;
    for (int i = t; i < EPB; i += 256) {
        int d = dst[base + i], s = src[base + i];
        int pD = atomicAdd(&fD[d >> 9], 1);      // LDS atomic
        pairsD[pD] = (unsigned)((s << 9) | (d & 511));
        int pS = atomicAdd(&fS[s >> 9], 1);
        pairsS[pS] = (unsigned short)(s & 511);
    }
}

// Pass 4: per dst-bucket: 512-bin LDS histogram -> rowptr (global, since buckets are
// contiguous), normD, and csr scatter. No global atomics anywhere.
__global__ __launch_bounds__(512) void csrbuild_kernel(const unsigned* __restrict__ pairsD,
        const int* __restrict__ cntsD, int* __restrict__ rowptr,
        float* __restrict__ normD, int* __restrict__ csr) {
    __shared__ int cnt[512], off[512];
    int t = threadIdx.x, b = blockIdx.x;
    int start = cntsD[b * ABLK];
    int end = (b == NBKT - 1) ? NE : cntsD[(b + 1) * ABLK];
    cnt[t] = 0;
    __syncthreads();
    for (int i = start + t; i < end; i += 512)
        atomicAdd(&cnt[pairsD[i] & 511], 1);
    __syncthreads();
    off[t] = cnt[t];
    __syncthreads();
    for (int o = 1; o < 512; o <<= 1) {         // inclusive scan
        int v = (t >= o) ? off[t - o] : 0;
        __syncthreads();
        off[t] += v;
        __syncthreads();
    }
    int excl = off[t] - cnt[t];
    int g = b * 512 + t;
    rowptr[g] = start + excl;                    // rowptr[NN] = NE falls out (tail cnt=0)
    normD[g] = rsqrtf(fmaxf((float)cnt[t], 1.0f));
    __syncthreads();
    off[t] = start + excl;                       // repurpose as fill counters
    __syncthreads();
    for (int i = start + t; i < end; i += 512) {
        unsigned p = pairsD[i];
        int pos = atomicAdd(&off[p & 511], 1);   // LDS atomic
        csr[pos] = (int)(p >> 9);
    }
}

// Pass 5: per src-bucket: 512-bin LDS histogram -> normS.
__global__ __launch_bounds__(512) void srccount_kernel(const unsigned short* __restrict__ pairsS,
        const int* __restrict__ cntsS, float* __restrict__ normS) {
    __shared__ int cnt[512];
    int t = threadIdx.x, b = blockIdx.x;
    int start = cntsS[b * ABLK];
    int end = (b == NBKT - 1) ? NE : cntsS[(b + 1) * ABLK];
    cnt[t] = 0;
    __syncthreads();
    for (int i = start + t; i < end; i += 512)
        atomicAdd(&cnt[pairsS[i]], 1);
    __syncthreads();
    normS[b * 512 + t] = rsqrtf(fmaxf((float)cnt[t], 1.0f));
}

// One wave per node: out[node][:] = sum over CSR neighbors of f(hs[s][:]). 128 wide.
// PRE: f = relu(.) * normS[s]  (layer-0, reads x directly). 4-deep MLP.
template<bool PRE>
__global__ __launch_bounds__(256) void gather128_kernel(const float* __restrict__ hs,
        const float* __restrict__ normS, const int* __restrict__ rowptr,
        const int* __restrict__ csr, float* __restrict__ out) {
    int node = __builtin_amdgcn_readfirstlane(blockIdx.x * 4 + (threadIdx.x >> 6));
    int lane = threadIdx.x & 63;
    if (node >= NN) return;
    int beg = rowptr[node], end = rowptr[node + 1];
    float2 a0 = {0.f, 0.f}, a1 = {0.f, 0.f}, a2 = {0.f, 0.f}, a3 = {0.f, 0.f};
    int j = beg;
    for (; j + 3 < end; j += 4) {
        int s0 = csr[j], s1 = csr[j + 1], s2 = csr[j + 2], s3 = csr[j + 3];
        float2 v0 = *(const float2*)(hs + (size_t)s0 * DF + lane * 2);
        float2 v1 = *(const float2*)(hs + (size_t)s1 * DF + lane * 2);
        float2 v2 = *(const float2*)(hs + (size_t)s2 * DF + lane * 2);
        float2 v3 = *(const float2*)(hs + (size_t)s3 * DF + lane * 2);
        if (PRE) {
            float w0 = normS[s0], w1 = normS[s1], w2 = normS[s2], w3 = normS[s3];
            v0.x = fmaxf(v0.x, 0.f) * w0; v0.y = fmaxf(v0.y, 0.f) * w0;
            v1.x = fmaxf(v1.x, 0.f) * w1; v1.y = fmaxf(v1.y, 0.f) * w1;
            v2.x = fmaxf(v2.x, 0.f) * w2; v2.y = fmaxf(v2.y, 0.f) * w2;
            v3.x = fmaxf(v3.x, 0.f) * w3; v3.y = fmaxf(v3.y, 0.f) * w3;
        }
        a0.x += v0.x; a0.y += v0.y;
        a1.x += v1.x; a1.y += v1.y;
        a2.x += v2.x; a2.y += v2.y;
        a3.x += v3.x; a3.y += v3.y;
    }
    for (; j < end; j++) {
        int s = csr[j];
        float2 v = *(const float2*)(hs + (size_t)s * DF + lane * 2);
        if (PRE) {
            float w = normS[s];
            v.x = fmaxf(v.x, 0.f) * w; v.y = fmaxf(v.y, 0.f) * w;
        }
        a0.x += v.x; a0.y += v.y;
    }
    a0.x += a1.x + a2.x + a3.x;
    a0.y += a1.y + a2.y + a3.y;
    *(float2*)(out + (size_t)node * DF + lane * 2) = a0;
}

// One wave per node, 48 wide, 4-deep MLP; fused epilogue: out = acc*normD[n] + b2[j]
__global__ __launch_bounds__(256) void gather48_kernel(const float* __restrict__ g,
        const int* __restrict__ rowptr, const int* __restrict__ csr,
        const float* __restrict__ normD, const float* __restrict__ b2,
        float* __restrict__ out) {
    int node = __builtin_amdgcn_readfirstlane(blockIdx.x * 4 + (threadIdx.x >> 6));
    int lane = threadIdx.x & 63;
    if (node >= NN) return;
    int beg = rowptr[node], end = rowptr[node + 1];
    float a0 = 0.f, a1 = 0.f, a2 = 0.f, a3 = 0.f;
    int j = beg;
    bool act = lane < NCP;
    for (; j + 3 < end; j += 4) {
        int s0 = csr[j], s1 = csr[j + 1], s2 = csr[j + 2], s3 = csr[j + 3];
        if (act) {
            a0 += g[(size_t)s0 * NCP + lane];
            a1 += g[(size_t)s1 * NCP + lane];
            a2 += g[(size_t)s2 * NCP + lane];
            a3 += g[(size_t)s3 * NCP + lane];
        }
    }
    for (; j < end; j++) {
        if (act) a0 += g[(size_t)csr[j] * NCP + lane];
    }
    if (lane < NC) out[(size_t)node * NC + lane] = (a0 + a1 + a2 + a3) * normD[node] + b2[lane];
}

// A[N][128] @ W[128][DOUT], 2 rows per thread (W-load reuse -> FMA-bound).
// EPI: out = relu?(acc*normD[row] + b[j]) * (NS ? normS[row] : 1), stride DOUT.
// !EPI: out = acc, stride DOUT_PAD (padding cols are 0 since Wl zero-padded).
template<int DOUT, int DOUT_PAD, bool EPI, bool ACT, bool NS>
__global__ __launch_bounds__(256) void gemm2_kernel(const float* __restrict__ A,
        const float* __restrict__ W, const float* __restrict__ b,
        const float* __restrict__ normD, const float* __restrict__ normS,
        float* __restrict__ out) {
    __shared__ float Wl[DF * DOUT_PAD];
    for (int i = threadIdx.x; i < DF * DOUT_PAD; i += 256) {
        int k = i / DOUT_PAD, j = i % DOUT_PAD;
        Wl[i] = (j < DOUT) ? W[k * DOUT + j] : 0.f;
    }
    __syncthreads();
    constexpr int TPR = DOUT_PAD / 4;  // threads per row-pair
    int gid = blockIdx.x * 256 + threadIdx.x;
    int p = gid / TPR;
    int jc = (gid % TPR) * 4;
    int r0 = p * 2;
    if (r0 >= NN) return;             // NN even -> r0+1 < NN too
    const float* a0 = A + (size_t)r0 * DF;
    const float* a1 = a0 + DF;
    float acc0[4] = {0.f, 0.f, 0.f, 0.f};
    float acc1[4] = {0.f, 0.f, 0.f, 0.f};
    for (int k0 = 0; k0 < DF; k0 += 4) {
        float4 x0 = *(const float4*)(a0 + k0);
        float4 x1 = *(const float4*)(a1 + k0);
        const float* xf0 = (const float*)&x0;
        const float* xf1 = (const float*)&x1;
        #pragma unroll
        for (int kk = 0; kk < 4; kk++) {
            float4 w = *(const float4*)(&Wl[(k0 + kk) * DOUT_PAD + jc]);
            float av0 = xf0[kk], av1 = xf1[kk];
            acc0[0] += av0 * w.x; acc0[1] += av0 * w.y;
            acc0[2] += av0 * w.z; acc0[3] += av0 * w.w;
            acc1[0] += av1 * w.x; acc1[1] += av1 * w.y;
            acc1[2] += av1 * w.z; acc1[3] += av1 * w.w;
        }
    }
    if (EPI) {
        float sd0 = normD[r0], sd1 = normD[r0 + 1];
        float ss0 = NS ? normS[r0] : 1.f, ss1 = NS ? normS[r0 + 1] : 1.f;
        #pragma unroll
        for (int i = 0; i < 4; i++) {
            int j = jc + i;
            if (j < DOUT) {
                float v0 = acc0[i] * sd0 + b[j];
                float v1 = acc1[i] * sd1 + b[j];
                if (ACT) { v0 = fmaxf(v0, 0.f); v1 = fmaxf(v1, 0.f); }
                out[(size_t)r0 * DOUT + j] = v0 * ss0;
                out[(size_t)(r0 + 1) * DOUT + j] = v1 * ss1;
            }
        }
    } else {
        *(float4*)(out + (size_t)r0 * DOUT_PAD + jc) =
            make_float4(acc0[0], acc0[1], acc0[2], acc0[3]);
        *(float4*)(out + (size_t)(r0 + 1) * DOUT_PAD + jc) =
            make_float4(acc1[0], acc1[1], acc1[2], acc1[3]);
    }
}

extern "C" void kernel_launch(void* const* d_in, const int* in_sizes, int n_in,
                              void* d_out, int out_size, void* d_ws, size_t ws_size,
                              hipStream_t stream) {
    const float* x   = (const float*)d_in[0];
    const int*   src = (const int*)d_in[1];
    const int*   dst = (const int*)d_in[2];
    const float* W0  = (const float*)d_in[3];
    const float* b0  = (const float*)d_in[4];
    const float* W1  = (const float*)d_in[5];
    const float* b1  = (const float*)d_in[6];
    const float* W2  = (const float*)d_in[7];
    const float* b2  = (const float*)d_in[8];
    float* out = (float*)d_out;

    // Persistent ws layout (NO memsets needed: every cell written before read):
    float* ws     = (float*)d_ws;
    float* normS  = ws;                              // NPAD floats
    float* normD  = ws + NPAD;                       // NPAD floats
    int*   rowptr = (int*)(ws + 2 * (size_t)NPAD);   // NPAD ints
    int*   csr    = rowptr + NPAD;                   // NE ints
    float* bufA   = (float*)(csr + NE);              // NN*DF floats
    float* bufB   = bufA + (size_t)NN * DF;          // NN*DF floats
    // Radix scratch aliased into bufA/bufB (both dead until the gathers/gemms):
    int* cntsD = (int*)bufA;                         // CLEN ints
    int* cntsS = cntsD + CLEN;                       // CLEN ints
    unsigned* pairsD = (unsigned*)bufB;              // NE u32
    unsigned short* pairsS = (unsigned short*)(pairsD + NE);  // NE u16

    // ---- graph prep: atomic-free radix CSR build ----
    bucketcount_kernel<<<ABLK, 256, 0, stream>>>(src, dst, cntsD, cntsS);
    bucketscan_kernel<<<2, 1024, 0, stream>>>(cntsD, cntsS);
    bucketscatter_kernel<<<ABLK, 256, 0, stream>>>(src, dst, cntsD, cntsS, pairsD, pairsS);
    csrbuild_kernel<<<NBKT, 512, 0, stream>>>(pairsD, cntsD, rowptr, normD, csr);
    srccount_kernel<<<NBKT, 512, 0, stream>>>(pairsS, cntsS, normS);

    // ---- layer 0: B = gather(relu(x)*normS); A = relu((B@W0)*normD + b0)*normS
    gather128_kernel<true><<<(NN + 3) / 4, 256, 0, stream>>>(x, normS, rowptr, csr, bufB);
    gemm2_kernel<DF, DF, true, true, true><<<NN / 2 * (DF / 4) / 256, 256, 0, stream>>>(
        bufB, W0, b0, normD, normS, bufA);

    // ---- layer 1: B = gather(A); A = relu((B@W1)*normD + b1)*normS
    gather128_kernel<false><<<(NN + 3) / 4, 256, 0, stream>>>(bufA, nullptr, rowptr, csr, bufB);
    gemm2_kernel<DF, DF, true, true, true><<<NN / 2 * (DF / 4) / 256, 256, 0, stream>>>(
        bufB, W1, b1, normD, normS, bufA);

    // ---- layer 2 (GEMM-first): B = A @ W2 (48-wide); out = gather48(B)*normD + b2
    gemm2_kernel<NC, NCP, false, false, false>
        <<<(NN / 2 * (NCP / 4) + 255) / 256, 256, 0, stream>>>(
        bufA, W2, nullptr, nullptr, nullptr, bufB);
    gather48_kernel<<<(NN + 3) / 4, 256, 0, stream>>>(bufB, rowptr, csr, normD, b2, out);
}

// Round 9
// 695.684 us; speedup vs baseline: 1.2083x; 1.2083x over previous
//
#include <hip/hip_runtime.h>

#define NN 100000
#define NE 1600000
#define DF 128
#define NC 47
#define NCP 48

constexpr int NPAD = 100352;        // = 196 * 512, padded node count
constexpr int NBKT = 196;           // radix buckets (512 nodes each)
constexpr int ABLK = 400;           // bucket count/scatter blocks
constexpr int EPB  = NE / ABLK;     // 4000 edges per block
constexpr int CLEN = NBKT * ABLK;   // 78400 per-block-per-bucket counts
constexpr int SB2  = (CLEN + 1023) / 1024;  // 77 scan blocks per array

// Pass 1: per-block LDS histograms of dst>>9 and src>>9 (no global atomics).
__global__ __launch_bounds__(256) void bucketcount_kernel(const int* __restrict__ src,
        const int* __restrict__ dst, int* __restrict__ cntsD, int* __restrict__ cntsS) {
    __shared__ int hD[NBKT], hS[NBKT];
    int t = threadIdx.x;
    if (t < NBKT) { hD[t] = 0; hS[t] = 0; }
    __syncthreads();
    int base = blockIdx.x * EPB;
    for (int i = t; i < EPB; i += 256) {
        atomicAdd(&hD[dst[base + i] >> 9], 1);   // LDS atomic (workgroup scope)
        atomicAdd(&hS[src[base + i] >> 9], 1);
    }
    __syncthreads();
    if (t < NBKT) {
        cntsD[t * ABLK + blockIdx.x] = hD[t];    // bucket-major for the scan
        cntsS[t * ABLK + blockIdx.x] = hS[t];
    }
}

// Pass 2 (3-pass parallel scan; round-3 lesson: scans must be multi-block).
// scan1: per-1024-block exclusive scan in place + block totals. y-dim picks array.
__global__ __launch_bounds__(1024) void scanA_kernel(int* __restrict__ cntsD,
        int* __restrict__ cntsS, int* __restrict__ bsum) {
    int* a = blockIdx.y ? cntsS : cntsD;
    __shared__ int tmp[1024];
    int t = threadIdx.x;
    int g = blockIdx.x * 1024 + t;
    int v = (g < CLEN) ? a[g] : 0;
    tmp[t] = v;
    __syncthreads();
    for (int off = 1; off < 1024; off <<= 1) {
        int u = (t >= off) ? tmp[t - off] : 0;
        __syncthreads();
        tmp[t] += u;
        __syncthreads();
    }
    if (g < CLEN) a[g] = tmp[t] - v;                       // exclusive within block
    if (t == 1023) bsum[blockIdx.y * SB2 + blockIdx.x] = tmp[t];
}

// scan2: scan the 77 block totals for each array (blockIdx.x picks array).
__global__ __launch_bounds__(128) void scanB_kernel(int* __restrict__ bsum) {
    __shared__ int tmp[128];
    int t = threadIdx.x;
    int* a = bsum + blockIdx.x * SB2;
    int v = (t < SB2) ? a[t] : 0;
    tmp[t] = v;
    __syncthreads();
    for (int off = 1; off < 128; off <<= 1) {
        int u = (t >= off) ? tmp[t - off] : 0;
        __syncthreads();
        tmp[t] += u;
        __syncthreads();
    }
    if (t < SB2) a[t] = tmp[t] - v;                        // exclusive, in place
}

// scan3: add block offsets.
__global__ __launch_bounds__(1024) void scanC_kernel(int* __restrict__ cntsD,
        int* __restrict__ cntsS, const int* __restrict__ bsum) {
    int* a = blockIdx.y ? cntsS : cntsD;
    int g = blockIdx.x * 1024 + threadIdx.x;
    if (g < CLEN) a[g] += bsum[blockIdx.y * SB2 + blockIdx.x];
}

// Pass 3: scatter edges into bucket-sorted arrays. Position = scanned block offset +
// LDS-atomic rank. pairsD packs (src<<9)|(dst&511); pairsS needs only src&511.
__global__ __launch_bounds__(256) void bucketscatter_kernel(const int* __restrict__ src,
        const int* __restrict__ dst, const int* __restrict__ cntsD,
        const int* __restrict__ cntsS, unsigned* __restrict__ pairsD,
        unsigned short* __restrict__ pairsS) {
    __shared__ int fD[NBKT], fS[NBKT];
    int t = threadIdx.x;
    if (t < NBKT) {
        fD[t] = cntsD[t * ABLK + blockIdx.x];
        fS[t] = cntsS[t * ABLK + blockIdx.x];
    }
    __syncthreads();
    int base = blockIdx.x * EPB;
    for (int i = t; i < EPB; i += 256) {
        int d = dst[base + i], s = src[base + i];
        int pD = atomicAdd(&fD[d >> 9], 1);      // LDS atomic
        pairsD[pD] = (unsigned)((s << 9) | (d & 511));
        int pS = atomicAdd(&fS[s >> 9], 1);
        pairsS[pS] = (unsigned short)(s & 511);
    }
}

// Pass 4: per dst-bucket: 512-bin LDS histogram -> rowptr, normD, csr scatter.
__global__ __launch_bounds__(512) void csrbuild_kernel(const unsigned* __restrict__ pairsD,
        const int* __restrict__ cntsD, int* __restrict__ rowptr,
        float* __restrict__ normD, int* __restrict__ csr) {
    __shared__ int cnt[512], off[512];
    int t = threadIdx.x, b = blockIdx.x;
    int start = cntsD[b * ABLK];
    int end = (b == NBKT - 1) ? NE : cntsD[(b + 1) * ABLK];
    cnt[t] = 0;
    __syncthreads();
    for (int i = start + t; i < end; i += 512)
        atomicAdd(&cnt[pairsD[i] & 511], 1);
    __syncthreads();
    off[t] = cnt[t];
    __syncthreads();
    for (int o = 1; o < 512; o <<= 1) {         // inclusive scan
        int v = (t >= o) ? off[t - o] : 0;
        __syncthreads();
        off[t] += v;
        __syncthreads();
    }
    int excl = off[t] - cnt[t];
    int g = b * 512 + t;
    rowptr[g] = start + excl;                    // rowptr[NN] = NE falls out (tail cnt=0)
    normD[g] = rsqrtf(fmaxf((float)cnt[t], 1.0f));
    __syncthreads();
    off[t] = start + excl;                       // repurpose as fill counters
    __syncthreads();
    for (int i = start + t; i < end; i += 512) {
        unsigned p = pairsD[i];
        int pos = atomicAdd(&off[p & 511], 1);   // LDS atomic
        csr[pos] = (int)(p >> 9);
    }
}

// Pass 5: per src-bucket: 512-bin LDS histogram -> normS.
__global__ __launch_bounds__(512) void srccount_kernel(const unsigned short* __restrict__ pairsS,
        const int* __restrict__ cntsS, float* __restrict__ normS) {
    __shared__ int cnt[512];
    int t = threadIdx.x, b = blockIdx.x;
    int start = cntsS[b * ABLK];
    int end = (b == NBKT - 1) ? NE : cntsS[(b + 1) * ABLK];
    cnt[t] = 0;
    __syncthreads();
    for (int i = start + t; i < end; i += 512)
        atomicAdd(&cnt[pairsS[i]], 1);
    __syncthreads();
    normS[b * 512 + t] = rsqrtf(fmaxf((float)cnt[t], 1.0f));
}

// One wave per node: out[node][:] = sum over CSR neighbors of f(hs[s][:]). 128 wide.
// PRE: f = relu(.) * normS[s]  (layer-0, reads x directly). 4-deep MLP.
template<bool PRE>
__global__ __launch_bounds__(256) void gather128_kernel(const float* __restrict__ hs,
        const float* __restrict__ normS, const int* __restrict__ rowptr,
        const int* __restrict__ csr, float* __restrict__ out) {
    int node = __builtin_amdgcn_readfirstlane(blockIdx.x * 4 + (threadIdx.x >> 6));
    int lane = threadIdx.x & 63;
    if (node >= NN) return;
    int beg = rowptr[node], end = rowptr[node + 1];
    float2 a0 = {0.f, 0.f}, a1 = {0.f, 0.f}, a2 = {0.f, 0.f}, a3 = {0.f, 0.f};
    int j = beg;
    for (; j + 3 < end; j += 4) {
        int s0 = csr[j], s1 = csr[j + 1], s2 = csr[j + 2], s3 = csr[j + 3];
        float2 v0 = *(const float2*)(hs + (size_t)s0 * DF + lane * 2);
        float2 v1 = *(const float2*)(hs + (size_t)s1 * DF + lane * 2);
        float2 v2 = *(const float2*)(hs + (size_t)s2 * DF + lane * 2);
        float2 v3 = *(const float2*)(hs + (size_t)s3 * DF + lane * 2);
        if (PRE) {
            float w0 = normS[s0], w1 = normS[s1], w2 = normS[s2], w3 = normS[s3];
            v0.x = fmaxf(v0.x, 0.f) * w0; v0.y = fmaxf(v0.y, 0.f) * w0;
            v1.x = fmaxf(v1.x, 0.f) * w1; v1.y = fmaxf(v1.y, 0.f) * w1;
            v2.x = fmaxf(v2.x, 0.f) * w2; v2.y = fmaxf(v2.y, 0.f) * w2;
            v3.x = fmaxf(v3.x, 0.f) * w3; v3.y = fmaxf(v3.y, 0.f) * w3;
        }
        a0.x += v0.x; a0.y += v0.y;
        a1.x += v1.x; a1.y += v1.y;
        a2.x += v2.x; a2.y += v2.y;
        a3.x += v3.x; a3.y += v3.y;
    }
    for (; j < end; j++) {
        int s = csr[j];
        float2 v = *(const float2*)(hs + (size_t)s * DF + lane * 2);
        if (PRE) {
            float w = normS[s];
            v.x = fmaxf(v.x, 0.f) * w; v.y = fmaxf(v.y, 0.f) * w;
        }
        a0.x += v.x; a0.y += v.y;
    }
    a0.x += a1.x + a2.x + a3.x;
    a0.y += a1.y + a2.y + a3.y;
    *(float2*)(out + (size_t)node * DF + lane * 2) = a0;
}

// One wave per node, 48 wide, 4-deep MLP; fused epilogue: out = acc*normD[n] + b2[j]
__global__ __launch_bounds__(256) void gather48_kernel(const float* __restrict__ g,
        const int* __restrict__ rowptr, const int* __restrict__ csr,
        const float* __restrict__ normD, const float* __restrict__ b2,
        float* __restrict__ out) {
    int node = __builtin_amdgcn_readfirstlane(blockIdx.x * 4 + (threadIdx.x >> 6));
    int lane = threadIdx.x & 63;
    if (node >= NN) return;
    int beg = rowptr[node], end = rowptr[node + 1];
    float a0 = 0.f, a1 = 0.f, a2 = 0.f, a3 = 0.f;
    int j = beg;
    bool act = lane < NCP;
    for (; j + 3 < end; j += 4) {
        int s0 = csr[j], s1 = csr[j + 1], s2 = csr[j + 2], s3 = csr[j + 3];
        if (act) {
            a0 += g[(size_t)s0 * NCP + lane];
            a1 += g[(size_t)s1 * NCP + lane];
            a2 += g[(size_t)s2 * NCP + lane];
            a3 += g[(size_t)s3 * NCP + lane];
        }
    }
    for (; j < end; j++) {
        if (act) a0 += g[(size_t)csr[j] * NCP + lane];
    }
    if (lane < NC) out[(size_t)node * NC + lane] = (a0 + a1 + a2 + a3) * normD[node] + b2[lane];
}

// A[N][128] @ W[128][DOUT], 2 rows per thread (W-load reuse -> FMA-bound).
// EPI: out = relu?(acc*normD[row] + b[j]) * (NS ? normS[row] : 1), stride DOUT.
// !EPI: out = acc, stride DOUT_PAD (padding cols are 0 since Wl zero-padded).
template<int DOUT, int DOUT_PAD, bool EPI, bool ACT, bool NS>
__global__ __launch_bounds__(256) void gemm2_kernel(const float* __restrict__ A,
        const float* __restrict__ W, const float* __restrict__ b,
        const float* __restrict__ normD, const float* __restrict__ normS,
        float* __restrict__ out) {
    __shared__ float Wl[DF * DOUT_PAD];
    for (int i = threadIdx.x; i < DF * DOUT_PAD; i += 256) {
        int k = i / DOUT_PAD, j = i % DOUT_PAD;
        Wl[i] = (j < DOUT) ? W[k * DOUT + j] : 0.f;
    }
    __syncthreads();
    constexpr int TPR = DOUT_PAD / 4;  // threads per row-pair
    int gid = blockIdx.x * 256 + threadIdx.x;
    int p = gid / TPR;
    int jc = (gid % TPR) * 4;
    int r0 = p * 2;
    if (r0 >= NN) return;             // NN even -> r0+1 < NN too
    const float* a0 = A + (size_t)r0 * DF;
    const float* a1 = a0 + DF;
    float acc0[4] = {0.f, 0.f, 0.f, 0.f};
    float acc1[4] = {0.f, 0.f, 0.f, 0.f};
    for (int k0 = 0; k0 < DF; k0 += 4) {
        float4 x0 = *(const float4*)(a0 + k0);
        float4 x1 = *(const float4*)(a1 + k0);
        const float* xf0 = (const float*)&x0;
        const float* xf1 = (const float*)&x1;
        #pragma unroll
        for (int kk = 0; kk < 4; kk++) {
            float4 w = *(const float4*)(&Wl[(k0 + kk) * DOUT_PAD + jc]);
            float av0 = xf0[kk], av1 = xf1[kk];
            acc0[0] += av0 * w.x; acc0[1] += av0 * w.y;
            acc0[2] += av0 * w.z; acc0[3] += av0 * w.w;
            acc1[0] += av1 * w.x; acc1[1] += av1 * w.y;
            acc1[2] += av1 * w.z; acc1[3] += av1 * w.w;
        }
    }
    if (EPI) {
        float sd0 = normD[r0], sd1 = normD[r0 + 1];
        float ss0 = NS ? normS[r0] : 1.f, ss1 = NS ? normS[r0 + 1] : 1.f;
        #pragma unroll
        for (int i = 0; i < 4; i++) {
            int j = jc + i;
            if (j < DOUT) {
                float v0 = acc0[i] * sd0 + b[j];
                float v1 = acc1[i] * sd1 + b[j];
                if (ACT) { v0 = fmaxf(v0, 0.f); v1 = fmaxf(v1, 0.f); }
                out[(size_t)r0 * DOUT + j] = v0 * ss0;
                out[(size_t)(r0 + 1) * DOUT + j] = v1 * ss1;
            }
        }
    } else {
        *(float4*)(out + (size_t)r0 * DOUT_PAD + jc) =
            make_float4(acc0[0], acc0[1], acc0[2], acc0[3]);
        *(float4*)(out + (size_t)(r0 + 1) * DOUT_PAD + jc) =
            make_float4(acc1[0], acc1[1], acc1[2], acc1[3]);
    }
}

extern "C" void kernel_launch(void* const* d_in, const int* in_sizes, int n_in,
                              void* d_out, int out_size, void* d_ws, size_t ws_size,
                              hipStream_t stream) {
    const float* x   = (const float*)d_in[0];
    const int*   src = (const int*)d_in[1];
    const int*   dst = (const int*)d_in[2];
    const float* W0  = (const float*)d_in[3];
    const float* b0  = (const float*)d_in[4];
    const float* W1  = (const float*)d_in[5];
    const float* b1  = (const float*)d_in[6];
    const float* W2  = (const float*)d_in[7];
    const float* b2  = (const float*)d_in[8];
    float* out = (float*)d_out;

    // Persistent ws layout (NO memsets needed: every cell written before read):
    float* ws     = (float*)d_ws;
    float* normS  = ws;                              // NPAD floats
    float* normD  = ws + NPAD;                       // NPAD floats
    int*   rowptr = (int*)(ws + 2 * (size_t)NPAD);   // NPAD ints
    int*   csr    = rowptr + NPAD;                   // NE ints
    float* bufA   = (float*)(csr + NE);              // NN*DF floats
    float* bufB   = bufA + (size_t)NN * DF;          // NN*DF floats
    // Radix scratch aliased into bufA/bufB (both dead until the gathers/gemms):
    int* cntsD = (int*)bufA;                         // CLEN ints
    int* cntsS = cntsD + CLEN;                       // CLEN ints
    int* bsum  = cntsS + CLEN;                       // 2*SB2 ints
    unsigned* pairsD = (unsigned*)bufB;              // NE u32
    unsigned short* pairsS = (unsigned short*)(pairsD + NE);  // NE u16

    // ---- graph prep: atomic-free radix CSR build ----
    bucketcount_kernel<<<ABLK, 256, 0, stream>>>(src, dst, cntsD, cntsS);
    scanA_kernel<<<dim3(SB2, 2), 1024, 0, stream>>>(cntsD, cntsS, bsum);
    scanB_kernel<<<2, 128, 0, stream>>>(bsum);
    scanC_kernel<<<dim3(SB2, 2), 1024, 0, stream>>>(cntsD, cntsS, bsum);
    bucketscatter_kernel<<<ABLK, 256, 0, stream>>>(src, dst, cntsD, cntsS, pairsD, pairsS);
    csrbuild_kernel<<<NBKT, 512, 0, stream>>>(pairsD, cntsD, rowptr, normD, csr);
    srccount_kernel<<<NBKT, 512, 0, stream>>>(pairsS, cntsS, normS);

    // ---- layer 0: B = gather(relu(x)*normS); A = relu((B@W0)*normD + b0)*normS
    gather128_kernel<true><<<(NN + 3) / 4, 256, 0, stream>>>(x, normS, rowptr, csr, bufB);
    gemm2_kernel<DF, DF, true, true, true><<<NN / 2 * (DF / 4) / 256, 256, 0, stream>>>(
        bufB, W0, b0, normD, normS, bufA);

    // ---- layer 1: B = gather(A); A = relu((B@W1)*normD + b1)*normS
    gather128_kernel<false><<<(NN + 3) / 4, 256, 0, stream>>>(bufA, nullptr, rowptr, csr, bufB);
    gemm2_kernel<DF, DF, true, true, true><<<NN / 2 * (DF / 4) / 256, 256, 0, stream>>>(
        bufB, W1, b1, normD, normS, bufA);

    // ---- layer 2 (GEMM-first): B = A @ W2 (48-wide); out = gather48(B)*normD + b2
    gemm2_kernel<NC, NCP, false, false, false>
        <<<(NN / 2 * (NCP / 4) + 255) / 256, 256, 0, stream>>>(
        bufA, W2, nullptr, nullptr, nullptr, bufB);
    gather48_kernel<<<(NN + 3) / 4, 256, 0, stream>>>(bufB, rowptr, csr, normD, b2, out);
}

// Round 13
// 607.656 us; speedup vs baseline: 1.3833x; 1.1449x over previous
//
#include <hip/hip_runtime.h>

#define NN 100000
#define NE 1600000
#define DF 128
#define NC 47
#define NCP 48

constexpr int NPAD = 100352;        // = 196 * 512, padded node count
constexpr int NBKT = 196;           // radix buckets (512 nodes each)
constexpr int ABLK = 400;           // bucket count/scatter blocks
constexpr int EPB  = NE / ABLK;     // 4000 edges per block
constexpr int CLEN = NBKT * ABLK;   // 78400 per-block-per-bucket counts
constexpr int SB2  = (CLEN + 1023) / 1024;  // 77 scan blocks per array

// Pass 1: per-block LDS histograms of dst>>9 and src>>9 (no global atomics).
__global__ __launch_bounds__(256) void bucketcount_kernel(const int* __restrict__ src,
        const int* __restrict__ dst, int* __restrict__ cntsD, int* __restrict__ cntsS) {
    __shared__ int hD[NBKT], hS[NBKT];
    int t = threadIdx.x;
    if (t < NBKT) { hD[t] = 0; hS[t] = 0; }
    __syncthreads();
    int base = blockIdx.x * EPB;
    for (int i = t; i < EPB; i += 256) {
        atomicAdd(&hD[dst[base + i] >> 9], 1);   // LDS atomic (workgroup scope)
        atomicAdd(&hS[src[base + i] >> 9], 1);
    }
    __syncthreads();
    if (t < NBKT) {
        cntsD[t * ABLK + blockIdx.x] = hD[t];    // bucket-major for the scan
        cntsS[t * ABLK + blockIdx.x] = hS[t];
    }
}

// Pass 2 (3-pass parallel scan). scanA: per-1024-block exclusive scan + block totals.
__global__ __launch_bounds__(1024) void scanA_kernel(int* __restrict__ cntsD,
        int* __restrict__ cntsS, int* __restrict__ bsum) {
    int* a = blockIdx.y ? cntsS : cntsD;
    __shared__ int tmp[1024];
    int t = threadIdx.x;
    int g = blockIdx.x * 1024 + t;
    int v = (g < CLEN) ? a[g] : 0;
    tmp[t] = v;
    __syncthreads();
    for (int off = 1; off < 1024; off <<= 1) {
        int u = (t >= off) ? tmp[t - off] : 0;
        __syncthreads();
        tmp[t] += u;
        __syncthreads();
    }
    if (g < CLEN) a[g] = tmp[t] - v;                       // exclusive within block
    if (t == 1023) bsum[blockIdx.y * SB2 + blockIdx.x] = tmp[t];
}

__global__ __launch_bounds__(128) void scanB_kernel(int* __restrict__ bsum) {
    __shared__ int tmp[128];
    int t = threadIdx.x;
    int* a = bsum + blockIdx.x * SB2;
    int v = (t < SB2) ? a[t] : 0;
    tmp[t] = v;
    __syncthreads();
    for (int off = 1; off < 128; off <<= 1) {
        int u = (t >= off) ? tmp[t - off] : 0;
        __syncthreads();
        tmp[t] += u;
        __syncthreads();
    }
    if (t < SB2) a[t] = tmp[t] - v;                        // exclusive, in place
}

__global__ __launch_bounds__(1024) void scanC_kernel(int* __restrict__ cntsD,
        int* __restrict__ cntsS, const int* __restrict__ bsum) {
    int* a = blockIdx.y ? cntsS : cntsD;
    int g = blockIdx.x * 1024 + threadIdx.x;
    if (g < CLEN) a[g] += bsum[blockIdx.y * SB2 + blockIdx.x];
}

// Pass 3: scatter edges into bucket-sorted arrays. Position = scanned block offset +
// LDS-atomic rank. pairsD packs (src<<9)|(dst&511); pairsS needs only src&511.
__global__ __launch_bounds__(256) void bucketscatter_kernel(const int* __restrict__ src,
        const int* __restrict__ dst, const int* __restrict__ cntsD,
        const int* __restrict__ cntsS, unsigned* __restrict__ pairsD,
        unsigned short* __restrict__ pairsS) {
    __shared__ int fD[NBKT], fS[NBKT];
    int t = threadIdx.x;
    if (t < NBKT) {
        fD[t] = cntsD[t * ABLK + blockIdx.x];
        fS[t] = cntsS[t * ABLK + blockIdx.x];
    }
    __syncthreads();
    int base = blockIdx.x * EPB;
    for (int i = t; i < EPB; i += 256) {
        int d = dst[base + i], s = src[base + i];
        int pD = atomicAdd(&fD[d >> 9], 1);      // LDS atomic
        pairsD[pD] = (unsigned)((s << 9) | (d & 511));
        int pS = atomicAdd(&fS[s >> 9], 1);
        pairsS[pS] = (unsigned short)(s & 511);
    }
}

// Pass 4: per dst-bucket: 512-bin LDS histogram -> rowptr, normD, csr scatter.
__global__ __launch_bounds__(512) void csrbuild_kernel(const unsigned* __restrict__ pairsD,
        const int* __restrict__ cntsD, int* __restrict__ rowptr,
        float* __restrict__ normD, int* __restrict__ csr) {
    __shared__ int cnt[512], off[512];
    int t = threadIdx.x, b = blockIdx.x;
    int start = cntsD[b * ABLK];
    int end = (b == NBKT - 1) ? NE : cntsD[(b + 1) * ABLK];
    cnt[t] = 0;
    __syncthreads();
    for (int i = start + t; i < end; i += 512)
        atomicAdd(&cnt[pairsD[i] & 511], 1);
    __syncthreads();
    off[t] = cnt[t];
    __syncthreads();
    for (int o = 1; o < 512; o <<= 1) {         // inclusive scan
        int v = (t >= o) ? off[t - o] : 0;
        __syncthreads();
        off[t] += v;
        __syncthreads();
    }
    int excl = off[t] - cnt[t];
    int g = b * 512 + t;
    rowptr[g] = start + excl;                    // rowptr[NN] = NE falls out (tail cnt=0)
    normD[g] = rsqrtf(fmaxf((float)cnt[t], 1.0f));
    __syncthreads();
    off[t] = start + excl;                       // repurpose as fill counters
    __syncthreads();
    for (int i = start + t; i < end; i += 512) {
        unsigned p = pairsD[i];
        int pos = atomicAdd(&off[p & 511], 1);   // LDS atomic
        csr[pos] = (int)(p >> 9);
    }
}

// Pass 5: per src-bucket: 512-bin LDS histogram -> normS.
__global__ __launch_bounds__(512) void srccount_kernel(const unsigned short* __restrict__ pairsS,
        const int* __restrict__ cntsS, float* __restrict__ normS) {
    __shared__ int cnt[512];
    int t = threadIdx.x, b = blockIdx.x;
    int start = cntsS[b * ABLK];
    int end = (b == NBKT - 1) ? NE : cntsS[(b + 1) * ABLK];
    cnt[t] = 0;
    __syncthreads();
    for (int i = start + t; i < end; i += 512)
        atomicAdd(&cnt[pairsS[i]], 1);
    __syncthreads();
    normS[b * 512 + t] = rsqrtf(fmaxf((float)cnt[t], 1.0f));
}

// One wave per node: out[node][:] = sum over CSR neighbors of f(hs[s][:]). 128 wide.
// PRE: f = relu(.) * normS[s]  (layer-0, reads x directly). 4-deep MLP.
template<bool PRE>
__global__ __launch_bounds__(256) void gather128_kernel(const float* __restrict__ hs,
        const float* __restrict__ normS, const int* __restrict__ rowptr,
        const int* __restrict__ csr, float* __restrict__ out) {
    int node = __builtin_amdgcn_readfirstlane(blockIdx.x * 4 + (threadIdx.x >> 6));
    int lane = threadIdx.x & 63;
    if (node >= NN) return;
    int beg = rowptr[node], end = rowptr[node + 1];
    float2 a0 = {0.f, 0.f}, a1 = {0.f, 0.f}, a2 = {0.f, 0.f}, a3 = {0.f, 0.f};
    int j = beg;
    for (; j + 3 < end; j += 4) {
        int s0 = csr[j], s1 = csr[j + 1], s2 = csr[j + 2], s3 = csr[j + 3];
        float2 v0 = *(const float2*)(hs + (size_t)s0 * DF + lane * 2);
        float2 v1 = *(const float2*)(hs + (size_t)s1 * DF + lane * 2);
        float2 v2 = *(const float2*)(hs + (size_t)s2 * DF + lane * 2);
        float2 v3 = *(const float2*)(hs + (size_t)s3 * DF + lane * 2);
        if (PRE) {
            float w0 = normS[s0], w1 = normS[s1], w2 = normS[s2], w3 = normS[s3];
            v0.x = fmaxf(v0.x, 0.f) * w0; v0.y = fmaxf(v0.y, 0.f) * w0;
            v1.x = fmaxf(v1.x, 0.f) * w1; v1.y = fmaxf(v1.y, 0.f) * w1;
            v2.x = fmaxf(v2.x, 0.f) * w2; v2.y = fmaxf(v2.y, 0.f) * w2;
            v3.x = fmaxf(v3.x, 0.f) * w3; v3.y = fmaxf(v3.y, 0.f) * w3;
        }
        a0.x += v0.x; a0.y += v0.y;
        a1.x += v1.x; a1.y += v1.y;
        a2.x += v2.x; a2.y += v2.y;
        a3.x += v3.x; a3.y += v3.y;
    }
    for (; j < end; j++) {
        int s = csr[j];
        float2 v = *(const float2*)(hs + (size_t)s * DF + lane * 2);
        if (PRE) {
            float w = normS[s];
            v.x = fmaxf(v.x, 0.f) * w; v.y = fmaxf(v.y, 0.f) * w;
        }
        a0.x += v.x; a0.y += v.y;
    }
    a0.x += a1.x + a2.x + a3.x;
    a0.y += a1.y + a2.y + a3.y;
    *(float2*)(out + (size_t)node * DF + lane * 2) = a0;
}

// One wave per node, 48 wide, 4-deep MLP; fused epilogue: out = acc*normD[n] + b2[j]
__global__ __launch_bounds__(256) void gather48_kernel(const float* __restrict__ g,
        const int* __restrict__ rowptr, const int* __restrict__ csr,
        const float* __restrict__ normD, const float* __restrict__ b2,
        float* __restrict__ out) {
    int node = __builtin_amdgcn_readfirstlane(blockIdx.x * 4 + (threadIdx.x >> 6));
    int lane = threadIdx.x & 63;
    if (node >= NN) return;
    int beg = rowptr[node], end = rowptr[node + 1];
    float a0 = 0.f, a1 = 0.f, a2 = 0.f, a3 = 0.f;
    int j = beg;
    bool act = lane < NCP;
    for (; j + 3 < end; j += 4) {
        int s0 = csr[j], s1 = csr[j + 1], s2 = csr[j + 2], s3 = csr[j + 3];
        if (act) {
            a0 += g[(size_t)s0 * NCP + lane];
            a1 += g[(size_t)s1 * NCP + lane];
            a2 += g[(size_t)s2 * NCP + lane];
            a3 += g[(size_t)s3 * NCP + lane];
        }
    }
    for (; j < end; j++) {
        if (act) a0 += g[(size_t)csr[j] * NCP + lane];
    }
    if (lane < NC) out[(size_t)node * NC + lane] = (a0 + a1 + a2 + a3) * normD[node] + b2[lane];
}

// A[N][128] @ W[128][DOUT], 4 rows per thread, 512-thread blocks.
// 64 FMA per {4 ds_read_b128 + 4 global float4} k-quad -> FMA-dominant; 64KB LDS
// with 512-thread blocks -> 2 blocks/CU = 16 waves (2x the 256-thread version).
// EPI: out = relu?(acc*normD[row] + b[j]) * (NS ? normS[row] : 1), stride DOUT.
// !EPI: out = acc, stride DOUT_PAD (padding cols are 0 since Wl zero-padded).
template<int DOUT, int DOUT_PAD, bool EPI, bool ACT, bool NS>
__global__ __launch_bounds__(512) void gemm4_kernel(const float* __restrict__ A,
        const float* __restrict__ W, const float* __restrict__ b,
        const float* __restrict__ normD, const float* __restrict__ normS,
        float* __restrict__ out) {
    __shared__ float Wl[DF * DOUT_PAD];
    for (int i = threadIdx.x; i < DF * DOUT_PAD; i += 512) {
        int k = i / DOUT_PAD, j = i % DOUT_PAD;
        Wl[i] = (j < DOUT) ? W[k * DOUT + j] : 0.f;
    }
    __syncthreads();
    constexpr int TPR = DOUT_PAD / 4;  // threads per 4-row group
    int gid = blockIdx.x * 512 + threadIdx.x;
    int p = gid / TPR;
    int jc = (gid % TPR) * 4;
    int r0 = p * 4;
    if (r0 >= NN) return;              // NN % 4 == 0 -> all 4 rows valid
    const float* a0 = A + (size_t)r0 * DF;
    float acc[4][4] = {};
    for (int k0 = 0; k0 < DF; k0 += 4) {
        float4 xr[4];
        #pragma unroll
        for (int r = 0; r < 4; r++) xr[r] = *(const float4*)(a0 + r * DF + k0);
        #pragma unroll
        for (int kk = 0; kk < 4; kk++) {
            float4 w = *(const float4*)(&Wl[(k0 + kk) * DOUT_PAD + jc]);
            #pragma unroll
            for (int r = 0; r < 4; r++) {
                float av = ((const float*)&xr[r])[kk];
                acc[r][0] += av * w.x; acc[r][1] += av * w.y;
                acc[r][2] += av * w.z; acc[r][3] += av * w.w;
            }
        }
    }
    if (EPI) {
        #pragma unroll
        for (int r = 0; r < 4; r++) {
            int row = r0 + r;
            float sd = normD[row];
            float ss = NS ? normS[row] : 1.f;
            #pragma unroll
            for (int i = 0; i < 4; i++) {
                int j = jc + i;
                if (j < DOUT) {
                    float v = acc[r][i] * sd + b[j];
                    if (ACT) v = fmaxf(v, 0.f);
                    out[(size_t)row * DOUT + j] = v * ss;
                }
            }
        }
    } else {
        #pragma unroll
        for (int r = 0; r < 4; r++) {
            *(float4*)(out + (size_t)(r0 + r) * DOUT_PAD + jc) =
                make_float4(acc[r][0], acc[r][1], acc[r][2], acc[r][3]);
        }
    }
}

extern "C" void kernel_launch(void* const* d_in, const int* in_sizes, int n_in,
                              void* d_out, int out_size, void* d_ws, size_t ws_size,
                              hipStream_t stream) {
    const float* x   = (const float*)d_in[0];
    const int*   src = (const int*)d_in[1];
    const int*   dst = (const int*)d_in[2];
    const float* W0  = (const float*)d_in[3];
    const float* b0  = (const float*)d_in[4];
    const float* W1  = (const float*)d_in[5];
    const float* b1  = (const float*)d_in[6];
    const float* W2  = (const float*)d_in[7];
    const float* b2  = (const float*)d_in[8];
    float* out = (float*)d_out;

    // Persistent ws layout (NO memsets needed: every cell written before read):
    float* ws     = (float*)d_ws;
    float* normS  = ws;                              // NPAD floats
    float* normD  = ws + NPAD;                       // NPAD floats
    int*   rowptr = (int*)(ws + 2 * (size_t)NPAD);   // NPAD ints
    int*   csr    = rowptr + NPAD;                   // NE ints
    float* bufA   = (float*)(csr + NE);              // NN*DF floats
    float* bufB   = bufA + (size_t)NN * DF;          // NN*DF floats
    // Radix scratch aliased into bufA/bufB (both dead until the gathers/gemms):
    int* cntsD = (int*)bufA;                         // CLEN ints
    int* cntsS = cntsD + CLEN;                       // CLEN ints
    int* bsum  = cntsS + CLEN;                       // 2*SB2 ints
    unsigned* pairsD = (unsigned*)bufB;              // NE u32
    unsigned short* pairsS = (unsigned short*)(pairsD + NE);  // NE u16

    // ---- graph prep: atomic-free radix CSR build ----
    bucketcount_kernel<<<ABLK, 256, 0, stream>>>(src, dst, cntsD, cntsS);
    scanA_kernel<<<dim3(SB2, 2), 1024, 0, stream>>>(cntsD, cntsS, bsum);
    scanB_kernel<<<2, 128, 0, stream>>>(bsum);
    scanC_kernel<<<dim3(SB2, 2), 1024, 0, stream>>>(cntsD, cntsS, bsum);
    bucketscatter_kernel<<<ABLK, 256, 0, stream>>>(src, dst, cntsD, cntsS, pairsD, pairsS);
    csrbuild_kernel<<<NBKT, 512, 0, stream>>>(pairsD, cntsD, rowptr, normD, csr);
    srccount_kernel<<<NBKT, 512, 0, stream>>>(pairsS, cntsS, normS);

    // ---- layer 0: B = gather(relu(x)*normS); A = relu((B@W0)*normD + b0)*normS
    gather128_kernel<true><<<(NN + 3) / 4, 256, 0, stream>>>(x, normS, rowptr, csr, bufB);
    gemm4_kernel<DF, DF, true, true, true>
        <<<(NN / 4 * (DF / 4) + 511) / 512, 512, 0, stream>>>(
        bufB, W0, b0, normD, normS, bufA);

    // ---- layer 1: B = gather(A); A = relu((B@W1)*normD + b1)*normS
    gather128_kernel<false><<<(NN + 3) / 4, 256, 0, stream>>>(bufA, nullptr, rowptr, csr, bufB);
    gemm4_kernel<DF, DF, true, true, true>
        <<<(NN / 4 * (DF / 4) + 511) / 512, 512, 0, stream>>>(
        bufB, W1, b1, normD, normS, bufA);

    // ---- layer 2 (GEMM-first): B = A @ W2 (48-wide); out = gather48(B)*normD + b2
    gemm4_kernel<NC, NCP, false, false, false>
        <<<(NN / 4 * (NCP / 4) + 511) / 512, 512, 0, stream>>>(
        bufA, W2, nullptr, nullptr, nullptr, bufB);
    gather48_kernel<<<(NN + 3) / 4, 256, 0, stream>>>(bufB, rowptr, csr, normD, b2, out);
}

// Round 14
// 604.445 us; speedup vs baseline: 1.3907x; 1.0053x over previous
//
#include <hip/hip_runtime.h>

#define NN 100000
#define NE 1600000
#define DF 128
#define NC 47
#define NCP 48

constexpr int NPAD = 100352;        // = 196 * 512, padded node count
constexpr int NBKT = 196;           // radix buckets (512 nodes each)
constexpr int ABLK = 400;           // bucket count/scatter blocks
constexpr int EPB  = NE / ABLK;     // 4000 edges per block
constexpr int CLEN = NBKT * ABLK;   // 78400 per-block-per-bucket counts
constexpr int SB2  = (CLEN + 1023) / 1024;  // 77 scan blocks per array

// Pass 1: per-block LDS histograms of dst>>9 and src>>9 (no global atomics).
__global__ __launch_bounds__(256) void bucketcount_kernel(const int* __restrict__ src,
        const int* __restrict__ dst, int* __restrict__ cntsD, int* __restrict__ cntsS) {
    __shared__ int hD[NBKT], hS[NBKT];
    int t = threadIdx.x;
    if (t < NBKT) { hD[t] = 0; hS[t] = 0; }
    __syncthreads();
    int base = blockIdx.x * EPB;
    for (int i = t; i < EPB; i += 256) {
        atomicAdd(&hD[dst[base + i] >> 9], 1);   // LDS atomic (workgroup scope)
        atomicAdd(&hS[src[base + i] >> 9], 1);
    }
    __syncthreads();
    if (t < NBKT) {
        cntsD[t * ABLK + blockIdx.x] = hD[t];    // bucket-major for the scan
        cntsS[t * ABLK + blockIdx.x] = hS[t];
    }
}

// Pass 2 (3-pass parallel scan). scanA: per-1024-block exclusive scan + block totals.
__global__ __launch_bounds__(1024) void scanA_kernel(int* __restrict__ cntsD,
        int* __restrict__ cntsS, int* __restrict__ bsum) {
    int* a = blockIdx.y ? cntsS : cntsD;
    __shared__ int tmp[1024];
    int t = threadIdx.x;
    int g = blockIdx.x * 1024 + t;
    int v = (g < CLEN) ? a[g] : 0;
    tmp[t] = v;
    __syncthreads();
    for (int off = 1; off < 1024; off <<= 1) {
        int u = (t >= off) ? tmp[t - off] : 0;
        __syncthreads();
        tmp[t] += u;
        __syncthreads();
    }
    if (g < CLEN) a[g] = tmp[t] - v;                       // exclusive within block
    if (t == 1023) bsum[blockIdx.y * SB2 + blockIdx.x] = tmp[t];
}

__global__ __launch_bounds__(128) void scanB_kernel(int* __restrict__ bsum) {
    __shared__ int tmp[128];
    int t = threadIdx.x;
    int* a = bsum + blockIdx.x * SB2;
    int v = (t < SB2) ? a[t] : 0;
    tmp[t] = v;
    __syncthreads();
    for (int off = 1; off < 128; off <<= 1) {
        int u = (t >= off) ? tmp[t - off] : 0;
        __syncthreads();
        tmp[t] += u;
        __syncthreads();
    }
    if (t < SB2) a[t] = tmp[t] - v;                        // exclusive, in place
}

__global__ __launch_bounds__(1024) void scanC_kernel(int* __restrict__ cntsD,
        int* __restrict__ cntsS, const int* __restrict__ bsum) {
    int* a = blockIdx.y ? cntsS : cntsD;
    int g = blockIdx.x * 1024 + threadIdx.x;
    if (g < CLEN) a[g] += bsum[blockIdx.y * SB2 + blockIdx.x];
}

// Pass 3: scatter edges into bucket-sorted arrays. Position = scanned block offset +
// LDS-atomic rank. pairsD packs (src<<9)|(dst&511); pairsS needs only src&511.
__global__ __launch_bounds__(256) void bucketscatter_kernel(const int* __restrict__ src,
        const int* __restrict__ dst, const int* __restrict__ cntsD,
        const int* __restrict__ cntsS, unsigned* __restrict__ pairsD,
        unsigned short* __restrict__ pairsS) {
    __shared__ int fD[NBKT], fS[NBKT];
    int t = threadIdx.x;
    if (t < NBKT) {
        fD[t] = cntsD[t * ABLK + blockIdx.x];
        fS[t] = cntsS[t * ABLK + blockIdx.x];
    }
    __syncthreads();
    int base = blockIdx.x * EPB;
    for (int i = t; i < EPB; i += 256) {
        int d = dst[base + i], s = src[base + i];
        int pD = atomicAdd(&fD[d >> 9], 1);      // LDS atomic
        pairsD[pD] = (unsigned)((s << 9) | (d & 511));
        int pS = atomicAdd(&fS[s >> 9], 1);
        pairsS[pS] = (unsigned short)(s & 511);
    }
}

// Pass 4: per dst-bucket: 512-bin LDS histogram -> rowptr, normD, csr scatter.
__global__ __launch_bounds__(512) void csrbuild_kernel(const unsigned* __restrict__ pairsD,
        const int* __restrict__ cntsD, int* __restrict__ rowptr,
        float* __restrict__ normD, int* __restrict__ csr) {
    __shared__ int cnt[512], off[512];
    int t = threadIdx.x, b = blockIdx.x;
    int start = cntsD[b * ABLK];
    int end = (b == NBKT - 1) ? NE : cntsD[(b + 1) * ABLK];
    cnt[t] = 0;
    __syncthreads();
    for (int i = start + t; i < end; i += 512)
        atomicAdd(&cnt[pairsD[i] & 511], 1);
    __syncthreads();
    off[t] = cnt[t];
    __syncthreads();
    for (int o = 1; o < 512; o <<= 1) {         // inclusive scan
        int v = (t >= o) ? off[t - o] : 0;
        __syncthreads();
        off[t] += v;
        __syncthreads();
    }
    int excl = off[t] - cnt[t];
    int g = b * 512 + t;
    rowptr[g] = start + excl;                    // rowptr[NN] = NE falls out (tail cnt=0)
    normD[g] = rsqrtf(fmaxf((float)cnt[t], 1.0f));
    __syncthreads();
    off[t] = start + excl;                       // repurpose as fill counters
    __syncthreads();
    for (int i = start + t; i < end; i += 512) {
        unsigned p = pairsD[i];
        int pos = atomicAdd(&off[p & 511], 1);   // LDS atomic
        csr[pos] = (int)(p >> 9);
    }
}

// Pass 5: per src-bucket: 512-bin LDS histogram -> normS.
__global__ __launch_bounds__(512) void srccount_kernel(const unsigned short* __restrict__ pairsS,
        const int* __restrict__ cntsS, float* __restrict__ normS) {
    __shared__ int cnt[512];
    int t = threadIdx.x, b = blockIdx.x;
    int start = cntsS[b * ABLK];
    int end = (b == NBKT - 1) ? NE : cntsS[(b + 1) * ABLK];
    cnt[t] = 0;
    __syncthreads();
    for (int i = start + t; i < end; i += 512)
        atomicAdd(&cnt[pairsS[i]], 1);
    __syncthreads();
    normS[b * 512 + t] = rsqrtf(fmaxf((float)cnt[t], 1.0f));
}

// One wave per node: out[node][:] = sum over CSR neighbors of f(hs[s][:]). 128 wide.
// PRE: f = relu(.) * normS[s]  (layer-0, reads x directly). 8-deep MLP.
template<bool PRE>
__global__ __launch_bounds__(256) void gather128_kernel(const float* __restrict__ hs,
        const float* __restrict__ normS, const int* __restrict__ rowptr,
        const int* __restrict__ csr, float* __restrict__ out) {
    int node = __builtin_amdgcn_readfirstlane(blockIdx.x * 4 + (threadIdx.x >> 6));
    int lane = threadIdx.x & 63;
    if (node >= NN) return;
    int beg = rowptr[node], end = rowptr[node + 1];
    float2 a0 = {0.f, 0.f}, a1 = {0.f, 0.f}, a2 = {0.f, 0.f}, a3 = {0.f, 0.f};
    int j = beg;
    for (; j + 7 < end; j += 8) {              // 8 rows in flight
        int s[8];
        #pragma unroll
        for (int q = 0; q < 8; q++) s[q] = csr[j + q];
        float2 v[8];
        #pragma unroll
        for (int q = 0; q < 8; q++)
            v[q] = *(const float2*)(hs + (size_t)s[q] * DF + lane * 2);
        if (PRE) {
            #pragma unroll
            for (int q = 0; q < 8; q++) {
                float w = normS[s[q]];
                v[q].x = fmaxf(v[q].x, 0.f) * w;
                v[q].y = fmaxf(v[q].y, 0.f) * w;
            }
        }
        a0.x += v[0].x + v[4].x; a0.y += v[0].y + v[4].y;
        a1.x += v[1].x + v[5].x; a1.y += v[1].y + v[5].y;
        a2.x += v[2].x + v[6].x; a2.y += v[2].y + v[6].y;
        a3.x += v[3].x + v[7].x; a3.y += v[3].y + v[7].y;
    }
    for (; j + 3 < end; j += 4) {              // 4-deep mid tail
        int s[4];
        #pragma unroll
        for (int q = 0; q < 4; q++) s[q] = csr[j + q];
        float2 v[4];
        #pragma unroll
        for (int q = 0; q < 4; q++)
            v[q] = *(const float2*)(hs + (size_t)s[q] * DF + lane * 2);
        if (PRE) {
            #pragma unroll
            for (int q = 0; q < 4; q++) {
                float w = normS[s[q]];
                v[q].x = fmaxf(v[q].x, 0.f) * w;
                v[q].y = fmaxf(v[q].y, 0.f) * w;
            }
        }
        a0.x += v[0].x; a0.y += v[0].y;
        a1.x += v[1].x; a1.y += v[1].y;
        a2.x += v[2].x; a2.y += v[2].y;
        a3.x += v[3].x; a3.y += v[3].y;
    }
    for (; j < end; j++) {
        int s = csr[j];
        float2 v = *(const float2*)(hs + (size_t)s * DF + lane * 2);
        if (PRE) {
            float w = normS[s];
            v.x = fmaxf(v.x, 0.f) * w; v.y = fmaxf(v.y, 0.f) * w;
        }
        a0.x += v.x; a0.y += v.y;
    }
    a0.x += a1.x + a2.x + a3.x;
    a0.y += a1.y + a2.y + a3.y;
    *(float2*)(out + (size_t)node * DF + lane * 2) = a0;
}

// One wave per node, 48 wide, 8-deep MLP; fused epilogue: out = acc*normD[n] + b2[j]
__global__ __launch_bounds__(256) void gather48_kernel(const float* __restrict__ g,
        const int* __restrict__ rowptr, const int* __restrict__ csr,
        const float* __restrict__ normD, const float* __restrict__ b2,
        float* __restrict__ out) {
    int node = __builtin_amdgcn_readfirstlane(blockIdx.x * 4 + (threadIdx.x >> 6));
    int lane = threadIdx.x & 63;
    if (node >= NN) return;
    int beg = rowptr[node], end = rowptr[node + 1];
    float a0 = 0.f, a1 = 0.f, a2 = 0.f, a3 = 0.f;
    int j = beg;
    bool act = lane < NCP;
    for (; j + 7 < end; j += 8) {
        int s[8];
        #pragma unroll
        for (int q = 0; q < 8; q++) s[q] = csr[j + q];
        if (act) {
            float v[8];
            #pragma unroll
            for (int q = 0; q < 8; q++) v[q] = g[(size_t)s[q] * NCP + lane];
            a0 += v[0] + v[4]; a1 += v[1] + v[5];
            a2 += v[2] + v[6]; a3 += v[3] + v[7];
        }
    }
    for (; j + 3 < end; j += 4) {
        int s[4];
        #pragma unroll
        for (int q = 0; q < 4; q++) s[q] = csr[j + q];
        if (act) {
            a0 += g[(size_t)s[0] * NCP + lane];
            a1 += g[(size_t)s[1] * NCP + lane];
            a2 += g[(size_t)s[2] * NCP + lane];
            a3 += g[(size_t)s[3] * NCP + lane];
        }
    }
    for (; j < end; j++) {
        if (act) a0 += g[(size_t)csr[j] * NCP + lane];
    }
    if (lane < NC) out[(size_t)node * NC + lane] = (a0 + a1 + a2 + a3) * normD[node] + b2[lane];
}

// A[N][128] @ W[128][DOUT], 4 rows per thread, 512-thread blocks.
// EPI: out = relu?(acc*normD[row] + b[j]) * (NS ? normS[row] : 1), stride DOUT.
// !EPI: out = acc, stride DOUT_PAD (padding cols are 0 since Wl zero-padded).
template<int DOUT, int DOUT_PAD, bool EPI, bool ACT, bool NS>
__global__ __launch_bounds__(512) void gemm4_kernel(const float* __restrict__ A,
        const float* __restrict__ W, const float* __restrict__ b,
        const float* __restrict__ normD, const float* __restrict__ normS,
        float* __restrict__ out) {
    __shared__ float Wl[DF * DOUT_PAD];
    for (int i = threadIdx.x; i < DF * DOUT_PAD; i += 512) {
        int k = i / DOUT_PAD, j = i % DOUT_PAD;
        Wl[i] = (j < DOUT) ? W[k * DOUT + j] : 0.f;
    }
    __syncthreads();
    constexpr int TPR = DOUT_PAD / 4;  // threads per 4-row group
    int gid = blockIdx.x * 512 + threadIdx.x;
    int p = gid / TPR;
    int jc = (gid % TPR) * 4;
    int r0 = p * 4;
    if (r0 >= NN) return;              // NN % 4 == 0 -> all 4 rows valid
    const float* a0 = A + (size_t)r0 * DF;
    float acc[4][4] = {};
    for (int k0 = 0; k0 < DF; k0 += 4) {
        float4 xr[4];
        #pragma unroll
        for (int r = 0; r < 4; r++) xr[r] = *(const float4*)(a0 + r * DF + k0);
        #pragma unroll
        for (int kk = 0; kk < 4; kk++) {
            float4 w = *(const float4*)(&Wl[(k0 + kk) * DOUT_PAD + jc]);
            #pragma unroll
            for (int r = 0; r < 4; r++) {
                float av = ((const float*)&xr[r])[kk];
                acc[r][0] += av * w.x; acc[r][1] += av * w.y;
                acc[r][2] += av * w.z; acc[r][3] += av * w.w;
            }
        }
    }
    if (EPI) {
        #pragma unroll
        for (int r = 0; r < 4; r++) {
            int row = r0 + r;
            float sd = normD[row];
            float ss = NS ? normS[row] : 1.f;
            #pragma unroll
            for (int i = 0; i < 4; i++) {
                int j = jc + i;
                if (j < DOUT) {
                    float v = acc[r][i] * sd + b[j];
                    if (ACT) v = fmaxf(v, 0.f);
                    out[(size_t)row * DOUT + j] = v * ss;
                }
            }
        }
    } else {
        #pragma unroll
        for (int r = 0; r < 4; r++) {
            *(float4*)(out + (size_t)(r0 + r) * DOUT_PAD + jc) =
                make_float4(acc[r][0], acc[r][1], acc[r][2], acc[r][3]);
        }
    }
}

extern "C" void kernel_launch(void* const* d_in, const int* in_sizes, int n_in,
                              void* d_out, int out_size, void* d_ws, size_t ws_size,
                              hipStream_t stream) {
    const float* x   = (const float*)d_in[0];
    const int*   src = (const int*)d_in[1];
    const int*   dst = (const int*)d_in[2];
    const float* W0  = (const float*)d_in[3];
    const float* b0  = (const float*)d_in[4];
    const float* W1  = (const float*)d_in[5];
    const float* b1  = (const float*)d_in[6];
    const float* W2  = (const float*)d_in[7];
    const float* b2  = (const float*)d_in[8];
    float* out = (float*)d_out;

    // Persistent ws layout (NO memsets needed: every cell written before read):
    float* ws     = (float*)d_ws;
    float* normS  = ws;                              // NPAD floats
    float* normD  = ws + NPAD;                       // NPAD floats
    int*   rowptr = (int*)(ws + 2 * (size_t)NPAD);   // NPAD ints
    int*   csr    = rowptr + NPAD;                   // NE ints
    float* bufA   = (float*)(csr + NE);              // NN*DF floats
    float* bufB   = bufA + (size_t)NN * DF;          // NN*DF floats
    // Radix scratch aliased into bufA/bufB (both dead until the gathers/gemms):
    int* cntsD = (int*)bufA;                         // CLEN ints
    int* cntsS = cntsD + CLEN;                       // CLEN ints
    int* bsum  = cntsS + CLEN;                       // 2*SB2 ints
    unsigned* pairsD = (unsigned*)bufB;              // NE u32
    unsigned short* pairsS = (unsigned short*)(pairsD + NE);  // NE u16

    // ---- graph prep: atomic-free radix CSR build ----
    bucketcount_kernel<<<ABLK, 256, 0, stream>>>(src, dst, cntsD, cntsS);
    scanA_kernel<<<dim3(SB2, 2), 1024, 0, stream>>>(cntsD, cntsS, bsum);
    scanB_kernel<<<2, 128, 0, stream>>>(bsum);
    scanC_kernel<<<dim3(SB2, 2), 1024, 0, stream>>>(cntsD, cntsS, bsum);
    bucketscatter_kernel<<<ABLK, 256, 0, stream>>>(src, dst, cntsD, cntsS, pairsD, pairsS);
    csrbuild_kernel<<<NBKT, 512, 0, stream>>>(pairsD, cntsD, rowptr, normD, csr);
    srccount_kernel<<<NBKT, 512, 0, stream>>>(pairsS, cntsS, normS);

    // ---- layer 0: B = gather(relu(x)*normS); A = relu((B@W0)*normD + b0)*normS
    gather128_kernel<true><<<(NN + 3) / 4, 256, 0, stream>>>(x, normS, rowptr, csr, bufB);
    gemm4_kernel<DF, DF, true, true, true>
        <<<(NN / 4 * (DF / 4) + 511) / 512, 512, 0, stream>>>(
        bufB, W0, b0, normD, normS, bufA);

    // ---- layer 1: B = gather(A); A = relu((B@W1)*normD + b1)*normS
    gather128_kernel<false><<<(NN + 3) / 4, 256, 0, stream>>>(bufA, nullptr, rowptr, csr, bufB);
    gemm4_kernel<DF, DF, true, true, true>
        <<<(NN / 4 * (DF / 4) + 511) / 512, 512, 0, stream>>>(
        bufB, W1, b1, normD, normS, bufA);

    // ---- layer 2 (GEMM-first): B = A @ W2 (48-wide); out = gather48(B)*normD + b2
    gemm4_kernel<NC, NCP, false, false, false>
        <<<(NN / 4 * (NCP / 4) + 511) / 512, 512, 0, stream>>>(
        bufA, W2, nullptr, nullptr, nullptr, bufB);
    gather48_kernel<<<(NN + 3) / 4, 256, 0, stream>>>(bufB, rowptr, csr, normD, b2, out);
}